// Round 1
// baseline (21627.588 us; speedup 1.0000x reference)
//
#include <hip/hip_runtime.h>
#include <hip/hip_bf16.h>
#include <hip/hip_cooperative_groups.h>

namespace cg = cooperative_groups;

#define B_   32
#define E_   512
#define H_   512
#define N_   50
#define T_   100
#define V_   32000
#define BT_  3200
#define VM1  31999
#define DELTA_ 0.125f

using f32x4  = __attribute__((ext_vector_type(4))) float;
using short8 = __attribute__((ext_vector_type(8))) short;

__device__ __forceinline__ float sigf(float x) { return 1.f / (1.f + expf(-x)); }

// dot of 256 floats: w from global (per-thread row), x from LDS (broadcast)
__device__ __forceinline__ float dot256(const float* __restrict__ w, const float* __restrict__ x) {
    float s = 0.f;
#pragma unroll 8
    for (int q = 0; q < 64; ++q) {
        float4 wv = *(const float4*)(w + q * 4);
        s += wv.x * x[q * 4] + wv.y * x[q * 4 + 1] + wv.z * x[q * 4 + 2] + wv.w * x[q * 4 + 3];
    }
    return s;
}

// ---------------- phase 0 kernels ----------------

__global__ __launch_bounds__(512) void k_init(const float* __restrict__ features,
                                              float* __restrict__ vout_cur,
                                              float* __restrict__ h0, float* __restrict__ c0) {
    int b = blockIdx.x, e = threadIdx.x;
    const float* fr = features + (size_t)(b * E_ + e) * N_;
    float s = 0.f;
    for (int n = 0; n < N_; ++n) s += fr[n];
    vout_cur[b * E_ + e] = s / 50.f;
    h0[b * H_ + e] = 0.f;
    c0[b * H_ + e] = 0.f;
}

__global__ __launch_bounds__(256) void k_gather(const int* __restrict__ captions,
                                                const float* __restrict__ etab,
                                                float* __restrict__ emb_mat) {
    int row = blockIdx.x;
    int cap = captions[row];
    const float* src = etab + (size_t)cap * E_;
    float* dst = emb_mat + (size_t)row * E_;
    for (int k = threadIdx.x; k < E_; k += 256) dst[k] = src[k];
}

// feats_lin[b][h][n] = relu(sum_e Wf[h][e]*features[b][e][n] + bf[h])
__global__ __launch_bounds__(256) void k_fl(const float* __restrict__ features,
                                            const float* __restrict__ Wf,
                                            const float* __restrict__ bf,
                                            float* __restrict__ fl) {
    __shared__ float fs[E_ * N_]; // 100KB
    int b = blockIdx.x >> 3, s = blockIdx.x & 7;
    for (int i = threadIdx.x; i < E_ * N_; i += 256) fs[i] = features[(size_t)b * E_ * N_ + i];
    __syncthreads();
    int h = s * 64 + (threadIdx.x >> 2);
    int nq = threadIdx.x & 3;
    int n0 = nq * 12 + (nq < 2 ? nq : 2);
    int cnt = (nq < 2) ? 13 : 12;
    float acc[13];
#pragma unroll
    for (int q = 0; q < 13; ++q) acc[q] = 0.f;
    const float4* wrow = (const float4*)(Wf + (size_t)h * E_);
    for (int e4 = 0; e4 < 128; ++e4) {
        float4 w = wrow[e4];
        const float* f0 = fs + (e4 * 4) * N_ + n0;
#pragma unroll
        for (int q = 0; q < 13; ++q)
            if (q < cnt) acc[q] += w.x * f0[q] + w.y * f0[N_ + q] + w.z * f0[2 * N_ + q] + w.w * f0[3 * N_ + q];
    }
    float bb = bf[h];
    for (int q = 0; q < cnt; ++q)
        fl[((size_t)b * H_ + h) * N_ + n0 + q] = fmaxf(acc[q] + bb, 0.f);
}

// feT[b][n][h] = sum_g We[h][g]*fl[b][g][n] + be[h]   (transposed store)
__global__ __launch_bounds__(256) void k_feT(const float* __restrict__ fl,
                                             const float* __restrict__ We,
                                             const float* __restrict__ be,
                                             float* __restrict__ feT) {
    __shared__ float fs[H_ * N_];
    int b = blockIdx.x >> 3, s = blockIdx.x & 7;
    for (int i = threadIdx.x; i < H_ * N_; i += 256) fs[i] = fl[(size_t)b * H_ * N_ + i];
    __syncthreads();
    int h = s * 64 + (threadIdx.x >> 2);
    int nq = threadIdx.x & 3;
    int n0 = nq * 12 + (nq < 2 ? nq : 2);
    int cnt = (nq < 2) ? 13 : 12;
    float acc[13];
#pragma unroll
    for (int q = 0; q < 13; ++q) acc[q] = 0.f;
    const float4* wrow = (const float4*)(We + (size_t)h * H_);
    for (int e4 = 0; e4 < 128; ++e4) {
        float4 w = wrow[e4];
        const float* f0 = fs + (e4 * 4) * N_ + n0;
#pragma unroll
        for (int q = 0; q < 13; ++q)
            if (q < cnt) acc[q] += w.x * f0[q] + w.y * f0[N_ + q] + w.z * f0[2 * N_ + q] + w.w * f0[3 * N_ + q];
    }
    float bb = be[h];
    for (int q = 0; q < cnt; ++q)
        feT[((size_t)b * N_ + n0 + q) * H_ + h] = acc[q] + bb;
}

// pre[row][j] = emb[row] . Wih[j][512:1024] + bih[j] + bhh[j]   (row = b*T+t)
__global__ __launch_bounds__(256) void k_pregemm(const float* __restrict__ emb,
                                                 const float* __restrict__ Wih,
                                                 const float* __restrict__ bih,
                                                 const float* __restrict__ bhh,
                                                 float* __restrict__ pre) {
    __shared__ float As[64][36];
    __shared__ float Bs[32][65];
    int m0 = blockIdx.x * 64, n0 = blockIdx.y * 64;
    int tid = threadIdx.x, tx = tid & 15, ty = tid >> 4;
    float acc[4][4];
#pragma unroll
    for (int i = 0; i < 4; ++i)
#pragma unroll
        for (int j = 0; j < 4; ++j) acc[i][j] = 0.f;
    int r = tid >> 2, kq = (tid & 3) * 8;
    for (int k0 = 0; k0 < 512; k0 += 32) {
        __syncthreads();
        float4 a0 = *(const float4*)(emb + (size_t)(m0 + r) * 512 + k0 + kq);
        float4 a1 = *(const float4*)(emb + (size_t)(m0 + r) * 512 + k0 + kq + 4);
        *(float4*)&As[r][kq] = a0;
        *(float4*)&As[r][kq + 4] = a1;
        float4 b0 = *(const float4*)(Wih + (size_t)(n0 + r) * 1024 + 512 + k0 + kq);
        float4 b1 = *(const float4*)(Wih + (size_t)(n0 + r) * 1024 + 512 + k0 + kq + 4);
        Bs[kq + 0][r] = b0.x; Bs[kq + 1][r] = b0.y; Bs[kq + 2][r] = b0.z; Bs[kq + 3][r] = b0.w;
        Bs[kq + 4][r] = b1.x; Bs[kq + 5][r] = b1.y; Bs[kq + 6][r] = b1.z; Bs[kq + 7][r] = b1.w;
        __syncthreads();
#pragma unroll
        for (int q = 0; q < 8; ++q) {
            float4 a_0 = *(const float4*)&As[ty * 4 + 0][q * 4];
            float4 a_1 = *(const float4*)&As[ty * 4 + 1][q * 4];
            float4 a_2 = *(const float4*)&As[ty * 4 + 2][q * 4];
            float4 a_3 = *(const float4*)&As[ty * 4 + 3][q * 4];
            const float* ap0 = (const float*)&a_0;
            const float* ap1 = (const float*)&a_1;
            const float* ap2 = (const float*)&a_2;
            const float* ap3 = (const float*)&a_3;
#pragma unroll
            for (int kk = 0; kk < 4; ++kk) {
                float bv0 = Bs[q * 4 + kk][tx * 4 + 0];
                float bv1 = Bs[q * 4 + kk][tx * 4 + 1];
                float bv2 = Bs[q * 4 + kk][tx * 4 + 2];
                float bv3 = Bs[q * 4 + kk][tx * 4 + 3];
                acc[0][0] += ap0[kk] * bv0; acc[0][1] += ap0[kk] * bv1; acc[0][2] += ap0[kk] * bv2; acc[0][3] += ap0[kk] * bv3;
                acc[1][0] += ap1[kk] * bv0; acc[1][1] += ap1[kk] * bv1; acc[1][2] += ap1[kk] * bv2; acc[1][3] += ap1[kk] * bv3;
                acc[2][0] += ap2[kk] * bv0; acc[2][1] += ap2[kk] * bv1; acc[2][2] += ap2[kk] * bv2; acc[2][3] += ap2[kk] * bv3;
                acc[3][0] += ap3[kk] * bv0; acc[3][1] += ap3[kk] * bv1; acc[3][2] += ap3[kk] * bv2; acc[3][3] += ap3[kk] * bv3;
            }
        }
    }
#pragma unroll
    for (int i = 0; i < 4; ++i)
#pragma unroll
        for (int j = 0; j < 4; ++j) {
            int row = m0 + ty * 4 + i, col = n0 + tx * 4 + j;
            pre[(size_t)row * 2048 + col] = acc[i][j] + bih[col] + bhh[col];
        }
}

__global__ __launch_bounds__(256) void k_wout_bf(const float* __restrict__ Wout,
                                                 __hip_bfloat16* __restrict__ wbf) {
    size_t i8 = ((size_t)blockIdx.x * 256 + threadIdx.x) * 8;
    if (i8 >= (size_t)V_ * 512) return;
    size_t row = i8 >> 9;
    union { __hip_bfloat16 h[8]; uint4 u; } ub;
    if (row < VM1) {
        float4 v0 = *(const float4*)(Wout + i8);
        float4 v1 = *(const float4*)(Wout + i8 + 4);
        ub.h[0] = __float2bfloat16(v0.x); ub.h[1] = __float2bfloat16(v0.y);
        ub.h[2] = __float2bfloat16(v0.z); ub.h[3] = __float2bfloat16(v0.w);
        ub.h[4] = __float2bfloat16(v1.x); ub.h[5] = __float2bfloat16(v1.y);
        ub.h[6] = __float2bfloat16(v1.z); ub.h[7] = __float2bfloat16(v1.w);
    } else {
#pragma unroll
        for (int i = 0; i < 8; ++i) ub.h[i] = __float2bfloat16(0.f);
    }
    *(uint4*)(wbf + i8) = ub.u;
}

// ---------------- phase 1: recurrence (cooperative, 32 WGs x 1024) ----------------

__global__ __launch_bounds__(1024) void k_recur(
    const float* __restrict__ Wih, const float* __restrict__ Whh,
    const float* __restrict__ Wlh, const float* __restrict__ blh,
    const float* __restrict__ Weh, const float* __restrict__ beh,
    const float* __restrict__ Wa, const float* __restrict__ ba,
    const float* __restrict__ Wlo, const float* __restrict__ blo,
    const float* __restrict__ pre, const float* __restrict__ fl, const float* __restrict__ feT,
    float* __restrict__ Hbuf, float* __restrict__ cbuf, float* __restrict__ vout_cur,
    float* __restrict__ vout_all, __hip_bfloat16* __restrict__ vout_bf) {
    cg::grid_group grid = cg::this_grid();
    const int wg = blockIdx.x;   // 0..31
    const int tid = threadIdx.x; // 0..1023

    __shared__ float X_s[32][258];
    __shared__ float gate_s[4][16][32];
    __shared__ float hs[512], hls[512], hes[512], us[512];
    __shared__ float p2[512][2];
    __shared__ float sp[50][17];
    __shared__ float att_s[50];
    __shared__ float sc_s[50];

    const int b_item = tid & 31;
    const int lr0 = tid >> 5; // 0..31
    const int g0 = lr0 >> 4;  // 0/1
    const int hq0 = lr0 & 15;
    const int rg0 = g0 * 512 + wg * 16 + hq0;
    const int rg1 = (g0 + 2) * 512 + wg * 16 + hq0;

    for (int t = 0; t < T_; ++t) {
        const int ping = t & 1;
        const float* hprev = Hbuf + ping * (32 * 512);
        float* hnew = Hbuf + (ping ^ 1) * (32 * 512);

        // ---------- Stage A: gates + LSTM ----------
        float acc0 = 0.f, acc1 = 0.f;
        for (int kc = 0; kc < 1024; kc += 256) {
            __syncthreads();
            {
                const int bb = tid >> 5, kk = (tid & 31) * 8;
                const float* src = (kc < 512) ? (vout_cur + bb * 512 + kc + kk)
                                              : (hprev + bb * 512 + (kc - 512) + kk);
                float4 v0 = *(const float4*)src;
                float4 v1 = *(const float4*)(src + 4);
                *(float2*)&X_s[bb][kk + 0] = make_float2(v0.x, v0.y);
                *(float2*)&X_s[bb][kk + 2] = make_float2(v0.z, v0.w);
                *(float2*)&X_s[bb][kk + 4] = make_float2(v1.x, v1.y);
                *(float2*)&X_s[bb][kk + 6] = make_float2(v1.z, v1.w);
            }
            __syncthreads();
            const float* w0 = (kc < 512) ? (Wih + (size_t)rg0 * 1024 + kc) : (Whh + (size_t)rg0 * 512 + (kc - 512));
            const float* w1 = (kc < 512) ? (Wih + (size_t)rg1 * 1024 + kc) : (Whh + (size_t)rg1 * 512 + (kc - 512));
            const float* xr = &X_s[b_item][0];
#pragma unroll 8
            for (int q = 0; q < 64; ++q) {
                float4 a = *(const float4*)(w0 + q * 4);
                float4 c4 = *(const float4*)(w1 + q * 4);
                float2 x01 = *(const float2*)(xr + q * 4);
                float2 x23 = *(const float2*)(xr + q * 4 + 2);
                acc0 += a.x * x01.x + a.y * x01.y + a.z * x23.x + a.w * x23.y;
                acc1 += c4.x * x01.x + c4.y * x01.y + c4.z * x23.x + c4.w * x23.y;
            }
        }
        const size_t prow = ((size_t)b_item * T_ + t) * 2048;
        acc0 += pre[prow + rg0];
        acc1 += pre[prow + rg1];
        __syncthreads();
        gate_s[g0][hq0][b_item] = acc0;
        gate_s[g0 + 2][hq0][b_item] = acc1;
        __syncthreads();
        if (tid < 512) {
            int bb = tid & 31, hq = tid >> 5;
            float gi = gate_s[0][hq][bb], gf = gate_s[1][hq][bb];
            float gg = gate_s[2][hq][bb], go = gate_s[3][hq][bb];
            int hidx = wg * 16 + hq;
            float cold = cbuf[bb * 512 + hidx];
            float cn = sigf(gf) * cold + sigf(gi) * tanhf(gg);
            float hn = sigf(go) * tanhf(cn);
            cbuf[bb * 512 + hidx] = cn;
            hnew[bb * 512 + hidx] = hn;
        }
        grid.sync();

        // ---------- Stage B: per-b attention chain (b = wg) ----------
        const int b = wg;
        if (tid < 512) hs[tid] = hnew[b * 512 + tid];
        __syncthreads();
        { // hl
            int j = tid >> 1, half = tid & 1;
            p2[j][half] = dot256(Wlh + (size_t)j * 512 + half * 256, hs + half * 256);
        }
        __syncthreads();
        if (tid < 512) hls[tid] = tanhf(p2[tid][0] + p2[tid][1] + blh[tid]);
        __syncthreads();
        { // he (no tanh)
            int j = tid >> 1, half = tid & 1;
            p2[j][half] = dot256(Weh + (size_t)j * 512 + half * 256, hls + half * 256);
        }
        __syncthreads();
        if (tid < 512) hes[tid] = p2[tid][0] + p2[tid][1] + beh[tid];
        __syncthreads();
        // scores
        if (tid < 800) {
            int n = tid >> 4, hc = tid & 15;
            const float* fe = feT + ((size_t)b * N_ + n) * 512 + hc * 32;
            const float* hep = hes + hc * 32;
            const float* wap = Wa + hc * 32;
            float s = 0.f;
#pragma unroll
            for (int q = 0; q < 32; ++q) s += wap[q] * tanhf(fe[q] + hep[q]);
            sp[n][hc] = s;
        }
        __syncthreads();
        if (tid < 50) {
            float s = ba[0];
#pragma unroll
            for (int q = 0; q < 16; ++q) s += sp[tid][q];
            sc_s[tid] = s;
        }
        __syncthreads();
        if (tid < 64) { // softmax over 50 in wave 0
            float v = (tid < 50) ? sc_s[tid] : -3.0e38f;
            float m = v;
#pragma unroll
            for (int s = 1; s < 64; s <<= 1) m = fmaxf(m, __shfl_xor(m, s, 64));
            float e = (tid < 50) ? expf(v - m) : 0.f;
            float sum = e;
#pragma unroll
            for (int s = 1; s < 64; s <<= 1) sum += __shfl_xor(sum, s, 64);
            if (tid < 50) att_s[tid] = e / sum;
        }
        __syncthreads();
        { // u = att.fl + hl
            int hh = tid >> 1, nh = tid & 1;
            const float* fr = fl + ((size_t)b * 512 + hh) * N_ + nh * 25;
            const float* ar = att_s + nh * 25;
            float s = 0.f;
#pragma unroll
            for (int q = 0; q < 25; ++q) s += ar[q] * fr[q];
            p2[hh][nh] = s;
        }
        __syncthreads();
        if (tid < 512) us[tid] = p2[tid][0] + p2[tid][1] + hls[tid];
        __syncthreads();
        { // vout
            int j = tid >> 1, half = tid & 1;
            p2[j][half] = dot256(Wlo + (size_t)j * 512 + half * 256, us + half * 256);
        }
        __syncthreads();
        if (tid < 512) {
            float vo = tanhf(p2[tid][0] + p2[tid][1] + blo[tid]);
            vout_cur[b * 512 + tid] = vo;
            size_t orow = (size_t)b * T_ + t;
            vout_all[orow * 512 + tid] = vo;
            vout_bf[orow * 512 + tid] = __float2bfloat16(vo);
        }
        grid.sync();
    }
}

// ---------------- phase 2: logits GEMM (bf16 MFMA) + tile maxes ----------------

#define LDT 56
__global__ __launch_bounds__(256) void k_logits(const __hip_bfloat16* __restrict__ A,
                                                const __hip_bfloat16* __restrict__ Bm,
                                                const float* __restrict__ bout,
                                                float* __restrict__ out,
                                                float* __restrict__ tilemax) {
    __shared__ __hip_bfloat16 As[128][LDT];
    __shared__ __hip_bfloat16 Bs[128][LDT];
    int m0 = blockIdx.x * 128, n0 = blockIdx.y * 128;
    int tid = threadIdx.x;
    int lane = tid & 63, w = tid >> 6, wr = w >> 1, wc = w & 1;
    f32x4 acc[4][4];
#pragma unroll
    for (int i = 0; i < 4; ++i)
#pragma unroll
        for (int j = 0; j < 4; ++j) acc[i][j] = (f32x4){0.f, 0.f, 0.f, 0.f};
    int srow = tid >> 2, skq = (tid & 3) * 8;
    for (int k0 = 0; k0 < 512; k0 += 32) {
        __syncthreads();
        *(uint4*)&As[srow][skq]      = *(const uint4*)(A + (size_t)(m0 + srow) * 512 + k0 + skq);
        *(uint4*)&As[srow + 64][skq] = *(const uint4*)(A + (size_t)(m0 + srow + 64) * 512 + k0 + skq);
        *(uint4*)&Bs[srow][skq]      = *(const uint4*)(Bm + (size_t)(n0 + srow) * 512 + k0 + skq);
        *(uint4*)&Bs[srow + 64][skq] = *(const uint4*)(Bm + (size_t)(n0 + srow + 64) * 512 + k0 + skq);
        __syncthreads();
        short8 av[4], bv[4];
#pragma unroll
        for (int m4 = 0; m4 < 4; ++m4)
            av[m4] = *(const short8*)&As[wr * 64 + m4 * 16 + (lane & 15)][(lane >> 4) * 8];
#pragma unroll
        for (int n4 = 0; n4 < 4; ++n4)
            bv[n4] = *(const short8*)&Bs[wc * 64 + n4 * 16 + (lane & 15)][(lane >> 4) * 8];
#pragma unroll
        for (int m4 = 0; m4 < 4; ++m4)
#pragma unroll
            for (int n4 = 0; n4 < 4; ++n4)
                acc[m4][n4] = __builtin_amdgcn_mfma_f32_16x16x32_bf16(av[m4], bv[n4], acc[m4][n4], 0, 0, 0);
    }
    float bo[4];
    int gcol4[4];
#pragma unroll
    for (int n4 = 0; n4 < 4; ++n4) {
        gcol4[n4] = n0 + wc * 64 + n4 * 16 + (lane & 15);
        bo[n4] = (gcol4[n4] < VM1) ? bout[gcol4[n4]] : 0.f;
    }
#pragma unroll
    for (int m4 = 0; m4 < 4; ++m4)
#pragma unroll
        for (int i = 0; i < 4; ++i) {
            size_t grow = m0 + wr * 64 + m4 * 16 + ((lane >> 4) << 2) + i;
            float rmax = -3.0e38f;
#pragma unroll
            for (int n4 = 0; n4 < 4; ++n4) {
                float val = acc[m4][n4][i] + bo[n4];
                if (gcol4[n4] < VM1) {
                    out[grow * VM1 + gcol4[n4]] = val;
                    rmax = fmaxf(rmax, val);
                }
            }
#pragma unroll
            for (int s = 1; s < 16; s <<= 1) rmax = fmaxf(rmax, __shfl_xor(rmax, s, 64));
            if ((lane & 15) == 0) tilemax[grow * 500 + (n0 >> 6) + wc] = rmax;
        }
}

// ---------------- phase 3: exact fp32 argmax refinement ----------------

__global__ __launch_bounds__(64) void k_argmax(const float* __restrict__ tilemax,
                                               const float* __restrict__ vout_all,
                                               const float* __restrict__ Wout,
                                               const float* __restrict__ bout,
                                               float* __restrict__ ids) {
    int r = blockIdx.x, lane = threadIdx.x;
    float m = -3.0e38f;
    for (int c = lane; c < 500; c += 64) m = fmaxf(m, tilemax[(size_t)r * 500 + c]);
#pragma unroll
    for (int s = 1; s < 64; s <<= 1) m = fmaxf(m, __shfl_xor(m, s, 64));
    float thr = m - DELTA_;
    float bestv = -3.0e38f;
    int bestj = 0x3fffffff;
    for (int c0 = 0; c0 < 500; c0 += 64) {
        int cc = c0 + lane;
        bool f = (cc < 500) && (tilemax[(size_t)r * 500 + cc] >= thr);
        unsigned long long mask = __ballot(f);
        while (mask) {
            int bit = __ffsll(mask) - 1;
            mask &= mask - 1;
            int chunk = c0 + bit;
            int j = chunk * 64 + lane;
            if (j < VM1) {
                const float* wr_ = Wout + (size_t)j * 512;
                const float* vr = vout_all + (size_t)r * 512;
                float s = 0.f;
#pragma unroll 4
                for (int k = 0; k < 128; ++k) {
                    float4 wv = *(const float4*)(wr_ + k * 4);
                    float4 vv = *(const float4*)(vr + k * 4);
                    s += wv.x * vv.x + wv.y * vv.y + wv.z * vv.z + wv.w * vv.w;
                }
                float val = s + bout[j];
                if (val > bestv || (val == bestv && j < bestj)) { bestv = val; bestj = j; }
            }
        }
    }
#pragma unroll
    for (int s = 1; s < 64; s <<= 1) {
        float ov = __shfl_xor(bestv, s, 64);
        int oj = __shfl_xor(bestj, s, 64);
        if (ov > bestv || (ov == bestv && oj < bestj)) { bestv = ov; bestj = oj; }
    }
    if (lane == 0) ids[r] = (float)bestj;
}

// ---------------- launcher ----------------

extern "C" void kernel_launch(void* const* d_in, const int* in_sizes, int n_in,
                              void* d_out, int out_size, void* d_ws, size_t ws_size,
                              hipStream_t stream) {
    const float* features = (const float*)d_in[0];
    const int* captions   = (const int*)d_in[2];
    const float* etab     = (const float*)d_in[3];
    const float* Wih      = (const float*)d_in[4];
    const float* bih      = (const float*)d_in[5];
    const float* Whh      = (const float*)d_in[6];
    const float* bhh      = (const float*)d_in[7];
    const float* Wf       = (const float*)d_in[8];
    const float* bf       = (const float*)d_in[9];
    const float* We       = (const float*)d_in[10];
    const float* be       = (const float*)d_in[11];
    const float* Wlh      = (const float*)d_in[12];
    const float* blh      = (const float*)d_in[13];
    const float* Weh      = (const float*)d_in[14];
    const float* beh      = (const float*)d_in[15];
    const float* Wa       = (const float*)d_in[16];
    const float* ba       = (const float*)d_in[17];
    const float* Wlo      = (const float*)d_in[18];
    const float* blo      = (const float*)d_in[19];
    const float* Wout     = (const float*)d_in[20];
    const float* bout     = (const float*)d_in[21];

    float* out = (float*)d_out;
    float* ids = out + (size_t)BT_ * VM1;

    char* ws = (char*)d_ws;
    size_t off = 0;
    auto alloc = [&](size_t bytes) {
        void* p = ws + off;
        off += (bytes + 255) & ~(size_t)255;
        return p;
    };
    float* pre      = (float*)alloc((size_t)BT_ * 2048 * 4);
    float* emb_mat  = (float*)alloc((size_t)BT_ * 512 * 4);
    float* fl       = (float*)alloc((size_t)B_ * 512 * 50 * 4);
    float* feT      = (float*)alloc((size_t)B_ * 50 * 512 * 4);
    float* vout_all = (float*)alloc((size_t)BT_ * 512 * 4);
    float* Hbuf     = (float*)alloc((size_t)2 * B_ * 512 * 4);
    float* cbuf     = (float*)alloc((size_t)B_ * 512 * 4);
    float* vout_cur = (float*)alloc((size_t)B_ * 512 * 4);
    float* tilemax  = (float*)alloc((size_t)BT_ * 500 * 4);
    __hip_bfloat16* wout_bf = (__hip_bfloat16*)alloc((size_t)V_ * 512 * 2);
    __hip_bfloat16* vout_bf = (__hip_bfloat16*)alloc((size_t)BT_ * 512 * 2);

    k_init<<<32, 512, 0, stream>>>(features, vout_cur, Hbuf, cbuf);
    k_gather<<<3200, 256, 0, stream>>>(captions, etab, emb_mat);
    k_fl<<<256, 256, 0, stream>>>(features, Wf, bf, fl);
    k_feT<<<256, 256, 0, stream>>>(fl, We, be, feT);
    k_pregemm<<<dim3(50, 32), 256, 0, stream>>>(emb_mat, Wih, bih, bhh, pre);
    k_wout_bf<<<8000, 256, 0, stream>>>(Wout, wout_bf);
    {
        void* args[] = { (void*)&Wih, (void*)&Whh, (void*)&Wlh, (void*)&blh,
                         (void*)&Weh, (void*)&beh, (void*)&Wa, (void*)&ba,
                         (void*)&Wlo, (void*)&blo, (void*)&pre, (void*)&fl, (void*)&feT,
                         (void*)&Hbuf, (void*)&cbuf, (void*)&vout_cur,
                         (void*)&vout_all, (void*)&vout_bf };
        hipLaunchCooperativeKernel((const void*)k_recur, dim3(32), dim3(1024), args, 0, stream);
    }
    k_logits<<<dim3(25, 250), 256, 0, stream>>>(vout_bf, wout_bf, bout, out, tilemax);
    k_argmax<<<3200, 64, 0, stream>>>(tilemax, vout_all, Wout, bout, ids);
}

// Round 3
// 11982.540 us; speedup vs baseline: 1.8049x; 1.8049x over previous
//
#include <hip/hip_runtime.h>
#include <hip/hip_bf16.h>
#include <hip/hip_cooperative_groups.h>

#define B_   32
#define E_   512
#define H_   512
#define N_   50
#define T_   100
#define V_   32000
#define BT_  3200
#define VM1  31999
#define DELTA_ 0.125f
#define G_   64

using f32x4  = __attribute__((ext_vector_type(4))) float;
using short8 = __attribute__((ext_vector_type(8))) short;

__device__ __forceinline__ float sigf(float x) { return 1.f / (1.f + expf(-x)); }

// ---------------- lightweight global barrier (monotonic counter) ----------------
__device__ __forceinline__ void gbar(unsigned int* __restrict__ ctr, unsigned int target) {
    __syncthreads();
    if (threadIdx.x == 0) {
        __threadfence();
        __hip_atomic_fetch_add(ctr, 1u, __ATOMIC_RELEASE, __HIP_MEMORY_SCOPE_AGENT);
        while (__hip_atomic_load(ctr, __ATOMIC_ACQUIRE, __HIP_MEMORY_SCOPE_AGENT) < target)
            __builtin_amdgcn_s_sleep(2);
        __builtin_amdgcn_fence(__ATOMIC_ACQUIRE, "agent");
    }
    __syncthreads();
}

// stage a [32][512] fp32 vector-set into LDS with XOR f4-swizzle (conflict-reduced reads)
__device__ __forceinline__ void stageX(float* __restrict__ Xs, const float* __restrict__ src, int tid) {
#pragma unroll
    for (int i = 0; i < 8; ++i) {
        int idx4 = i * 512 + tid;              // float4 index 0..4095
        int b = idx4 >> 7, g4 = idx4 & 127;
        float4 v = *(const float4*)(src + ((size_t)idx4 << 2));
        *(float4*)(Xs + b * 512 + ((g4 ^ (b & 7)) << 2)) = v;
    }
}

// ---------------- phase 0 kernels ----------------

__global__ __launch_bounds__(512) void k_init(const float* __restrict__ features,
                                              float* __restrict__ vout_cur,
                                              float* __restrict__ Hbuf,
                                              unsigned int* __restrict__ bar) {
    int b = blockIdx.x, e = threadIdx.x;
    const float* fr = features + (size_t)(b * E_ + e) * N_;
    float s = 0.f;
    for (int n = 0; n < N_; ++n) s += fr[n];
    vout_cur[b * E_ + e] = s / 50.f;
    Hbuf[b * H_ + e] = 0.f;
    Hbuf[B_ * H_ + b * H_ + e] = 0.f;
    if (b == 0 && e < 16) bar[e] = 0u;
}

__global__ __launch_bounds__(256) void k_gather(const int* __restrict__ captions,
                                                const float* __restrict__ etab,
                                                float* __restrict__ emb_mat) {
    int row = blockIdx.x;
    int cap = captions[row];
    const float* src = etab + (size_t)cap * E_;
    float* dst = emb_mat + (size_t)row * E_;
    for (int k = threadIdx.x; k < E_; k += 256) dst[k] = src[k];
}

__global__ __launch_bounds__(256) void k_fl(const float* __restrict__ features,
                                            const float* __restrict__ Wf,
                                            const float* __restrict__ bf,
                                            float* __restrict__ fl) {
    __shared__ float fs[E_ * N_];
    int b = blockIdx.x >> 3, s = blockIdx.x & 7;
    for (int i = threadIdx.x; i < E_ * N_; i += 256) fs[i] = features[(size_t)b * E_ * N_ + i];
    __syncthreads();
    int h = s * 64 + (threadIdx.x >> 2);
    int nq = threadIdx.x & 3;
    int n0 = nq * 12 + (nq < 2 ? nq : 2);
    int cnt = (nq < 2) ? 13 : 12;
    float acc[13];
#pragma unroll
    for (int q = 0; q < 13; ++q) acc[q] = 0.f;
    const float4* wrow = (const float4*)(Wf + (size_t)h * E_);
    for (int e4 = 0; e4 < 128; ++e4) {
        float4 w = wrow[e4];
        const float* f0 = fs + (e4 * 4) * N_ + n0;
#pragma unroll
        for (int q = 0; q < 13; ++q)
            if (q < cnt) acc[q] += w.x * f0[q] + w.y * f0[N_ + q] + w.z * f0[2 * N_ + q] + w.w * f0[3 * N_ + q];
    }
    float bb = bf[h];
    for (int q = 0; q < cnt; ++q)
        fl[((size_t)b * H_ + h) * N_ + n0 + q] = fmaxf(acc[q] + bb, 0.f);
}

__global__ __launch_bounds__(256) void k_feT(const float* __restrict__ fl,
                                             const float* __restrict__ We,
                                             const float* __restrict__ be,
                                             float* __restrict__ feT) {
    __shared__ float fs[H_ * N_];
    int b = blockIdx.x >> 3, s = blockIdx.x & 7;
    for (int i = threadIdx.x; i < H_ * N_; i += 256) fs[i] = fl[(size_t)b * H_ * N_ + i];
    __syncthreads();
    int h = s * 64 + (threadIdx.x >> 2);
    int nq = threadIdx.x & 3;
    int n0 = nq * 12 + (nq < 2 ? nq : 2);
    int cnt = (nq < 2) ? 13 : 12;
    float acc[13];
#pragma unroll
    for (int q = 0; q < 13; ++q) acc[q] = 0.f;
    const float4* wrow = (const float4*)(We + (size_t)h * H_);
    for (int e4 = 0; e4 < 128; ++e4) {
        float4 w = wrow[e4];
        const float* f0 = fs + (e4 * 4) * N_ + n0;
#pragma unroll
        for (int q = 0; q < 13; ++q)
            if (q < cnt) acc[q] += w.x * f0[q] + w.y * f0[N_ + q] + w.z * f0[2 * N_ + q] + w.w * f0[3 * N_ + q];
    }
    float bb = be[h];
    for (int q = 0; q < cnt; ++q)
        feT[((size_t)b * N_ + n0 + q) * H_ + h] = acc[q] + bb;
}

__global__ __launch_bounds__(256) void k_pregemm(const float* __restrict__ emb,
                                                 const float* __restrict__ Wih,
                                                 const float* __restrict__ bih,
                                                 const float* __restrict__ bhh,
                                                 float* __restrict__ pre) {
    __shared__ float As[64][36];
    __shared__ float Bs[32][65];
    int m0 = blockIdx.x * 64, n0 = blockIdx.y * 64;
    int tid = threadIdx.x, tx = tid & 15, ty = tid >> 4;
    float acc[4][4];
#pragma unroll
    for (int i = 0; i < 4; ++i)
#pragma unroll
        for (int j = 0; j < 4; ++j) acc[i][j] = 0.f;
    int r = tid >> 2, kq = (tid & 3) * 8;
    for (int k0 = 0; k0 < 512; k0 += 32) {
        __syncthreads();
        float4 a0 = *(const float4*)(emb + (size_t)(m0 + r) * 512 + k0 + kq);
        float4 a1 = *(const float4*)(emb + (size_t)(m0 + r) * 512 + k0 + kq + 4);
        *(float4*)&As[r][kq] = a0;
        *(float4*)&As[r][kq + 4] = a1;
        float4 b0 = *(const float4*)(Wih + (size_t)(n0 + r) * 1024 + 512 + k0 + kq);
        float4 b1 = *(const float4*)(Wih + (size_t)(n0 + r) * 1024 + 512 + k0 + kq + 4);
        Bs[kq + 0][r] = b0.x; Bs[kq + 1][r] = b0.y; Bs[kq + 2][r] = b0.z; Bs[kq + 3][r] = b0.w;
        Bs[kq + 4][r] = b1.x; Bs[kq + 5][r] = b1.y; Bs[kq + 6][r] = b1.z; Bs[kq + 7][r] = b1.w;
        __syncthreads();
#pragma unroll
        for (int q = 0; q < 8; ++q) {
            float4 a_0 = *(const float4*)&As[ty * 4 + 0][q * 4];
            float4 a_1 = *(const float4*)&As[ty * 4 + 1][q * 4];
            float4 a_2 = *(const float4*)&As[ty * 4 + 2][q * 4];
            float4 a_3 = *(const float4*)&As[ty * 4 + 3][q * 4];
            const float* ap0 = (const float*)&a_0;
            const float* ap1 = (const float*)&a_1;
            const float* ap2 = (const float*)&a_2;
            const float* ap3 = (const float*)&a_3;
#pragma unroll
            for (int kk = 0; kk < 4; ++kk) {
                float bv0 = Bs[q * 4 + kk][tx * 4 + 0];
                float bv1 = Bs[q * 4 + kk][tx * 4 + 1];
                float bv2 = Bs[q * 4 + kk][tx * 4 + 2];
                float bv3 = Bs[q * 4 + kk][tx * 4 + 3];
                acc[0][0] += ap0[kk] * bv0; acc[0][1] += ap0[kk] * bv1; acc[0][2] += ap0[kk] * bv2; acc[0][3] += ap0[kk] * bv3;
                acc[1][0] += ap1[kk] * bv0; acc[1][1] += ap1[kk] * bv1; acc[1][2] += ap1[kk] * bv2; acc[1][3] += ap1[kk] * bv3;
                acc[2][0] += ap2[kk] * bv0; acc[2][1] += ap2[kk] * bv1; acc[2][2] += ap2[kk] * bv2; acc[2][3] += ap2[kk] * bv3;
                acc[3][0] += ap3[kk] * bv0; acc[3][1] += ap3[kk] * bv1; acc[3][2] += ap3[kk] * bv2; acc[3][3] += ap3[kk] * bv3;
            }
        }
    }
#pragma unroll
    for (int i = 0; i < 4; ++i)
#pragma unroll
        for (int j = 0; j < 4; ++j) {
            int row = m0 + ty * 4 + i, col = n0 + tx * 4 + j;
            pre[(size_t)row * 2048 + col] = acc[i][j] + bih[col] + bhh[col];
        }
}

__global__ __launch_bounds__(256) void k_wout_bf(const float* __restrict__ Wout,
                                                 __hip_bfloat16* __restrict__ wbf) {
    size_t i8 = ((size_t)blockIdx.x * 256 + threadIdx.x) * 8;
    if (i8 >= (size_t)V_ * 512) return;
    size_t row = i8 >> 9;
    union { __hip_bfloat16 h[8]; uint4 u; } ub;
    if (row < VM1) {
        float4 v0 = *(const float4*)(Wout + i8);
        float4 v1 = *(const float4*)(Wout + i8 + 4);
        ub.h[0] = __float2bfloat16(v0.x); ub.h[1] = __float2bfloat16(v0.y);
        ub.h[2] = __float2bfloat16(v0.z); ub.h[3] = __float2bfloat16(v0.w);
        ub.h[4] = __float2bfloat16(v1.x); ub.h[5] = __float2bfloat16(v1.y);
        ub.h[6] = __float2bfloat16(v1.z); ub.h[7] = __float2bfloat16(v1.w);
    } else {
#pragma unroll
        for (int i = 0; i < 8; ++i) ub.h[i] = __float2bfloat16(0.f);
    }
    *(uint4*)(wbf + i8) = ub.u;
}

// ---------------- phase 1: recurrence (64 WGs x 512, row-partitioned, flag barriers) ----------------

template<int ACT>
__device__ __forceinline__ void gemv_stage(const float* __restrict__ W, const float* __restrict__ bias,
                                           const float* __restrict__ srcvec, float* __restrict__ dst,
                                           float* __restrict__ Xs, float (*__restrict__ p2)[32][2],
                                           int wg, int tid) {
    __syncthreads();
    stageX(Xs, srcvec, tid);
    __syncthreads();
    {
        int b = tid & 31, rp = tid >> 5, row = rp >> 1, kh = rp & 1;
        int rg = wg * 8 + row;
        const float* w = W + (size_t)rg * 512 + kh * 256;
        const float* xb = Xs + b * 512;
        int gb = kh * 64;
        float s = 0.f;
#pragma unroll 8
        for (int q = 0; q < 64; ++q) {
            float4 xv = *(const float4*)(xb + (((gb + q) ^ (b & 7)) << 2));
            float4 wv = *(const float4*)(w + q * 4);
            s += wv.x * xv.x + wv.y * xv.y + wv.z * xv.z + wv.w * xv.w;
        }
        p2[row][b][kh] = s;
    }
    __syncthreads();
    if (tid < 256) {
        int b = tid & 31, row = tid >> 5;
        int rg = wg * 8 + row;
        float v = p2[row][b][0] + p2[row][b][1] + bias[rg];
        if (ACT) v = tanhf(v);
        dst[b * 512 + rg] = v;
    }
}

__global__ __launch_bounds__(512) void k_recur(
    const float* __restrict__ Wih, const float* __restrict__ Whh,
    const float* __restrict__ Wlh, const float* __restrict__ blh,
    const float* __restrict__ Weh, const float* __restrict__ beh,
    const float* __restrict__ Wa, const float* __restrict__ ba,
    const float* __restrict__ Wlo, const float* __restrict__ blo,
    const float* __restrict__ pre, const float* __restrict__ fl, const float* __restrict__ feT,
    float* __restrict__ Hbuf, float* __restrict__ vout_cur,
    float* __restrict__ hlbuf, float* __restrict__ hebuf, float* __restrict__ ubuf,
    float* __restrict__ vout_all, __hip_bfloat16* __restrict__ vout_bf,
    unsigned int* __restrict__ bar) {
    const int wg = blockIdx.x;   // 0..63
    const int tid = threadIdx.x; // 0..511

    __shared__ float Xs[32 * 512];     // 64KB, XOR-swizzled x vectors
    __shared__ float gs2[32][32][2];   // gate partials [row_loc][b][khalf]
    __shared__ float p2[8][32][2];
    __shared__ float c_lds[8][32];     // persistent cell state (this WG's h rows)
    __shared__ float hes_s[512];
    __shared__ float sp[50][17];
    __shared__ float sc_s[50];
    __shared__ float att_s[50];

    if (tid < 256) c_lds[tid >> 5][tid & 31] = 0.f;

    const int b = tid & 31;
    const int kh = (tid >> 5) & 1;
    const int rr = tid >> 6;           // 0..7
    const int ggate = rr >> 1, hbase = (rr & 1) * 4;
    const int rg0 = ggate * 512 + wg * 8 + hbase;

    for (int t = 0; t < T_; ++t) {
        const int ping = t & 1;
        const float* hprev = Hbuf + ping * (B_ * H_);
        float* hnew = Hbuf + (ping ^ 1) * (B_ * H_);
        const unsigned int tgt = (unsigned int)(t + 1) * G_;

        // ---------- S1: gates + LSTM ----------
        float a0 = 0.f, a1 = 0.f, a2 = 0.f, a3 = 0.f;
        for (int kc = 0; kc < 2; ++kc) {
            __syncthreads();
            stageX(Xs, kc ? hprev : vout_cur, tid);
            __syncthreads();
            const float* wb = kc ? Whh : Wih;
            const size_t wst = kc ? 512 : 1024;
            const float* w0 = wb + (size_t)(rg0 + 0) * wst + kh * 256;
            const float* w1 = wb + (size_t)(rg0 + 1) * wst + kh * 256;
            const float* w2 = wb + (size_t)(rg0 + 2) * wst + kh * 256;
            const float* w3 = wb + (size_t)(rg0 + 3) * wst + kh * 256;
            const float* xb = Xs + b * 512;
            const int gb = kh * 64;
#pragma unroll 4
            for (int q = 0; q < 64; ++q) {
                float4 xv = *(const float4*)(xb + (((gb + q) ^ (b & 7)) << 2));
                float4 v0 = *(const float4*)(w0 + q * 4);
                float4 v1 = *(const float4*)(w1 + q * 4);
                float4 v2 = *(const float4*)(w2 + q * 4);
                float4 v3 = *(const float4*)(w3 + q * 4);
                a0 += v0.x * xv.x + v0.y * xv.y + v0.z * xv.z + v0.w * xv.w;
                a1 += v1.x * xv.x + v1.y * xv.y + v1.z * xv.z + v1.w * xv.w;
                a2 += v2.x * xv.x + v2.y * xv.y + v2.z * xv.z + v2.w * xv.w;
                a3 += v3.x * xv.x + v3.y * xv.y + v3.z * xv.z + v3.w * xv.w;
            }
        }
        gs2[rr * 4 + 0][b][kh] = a0;
        gs2[rr * 4 + 1][b][kh] = a1;
        gs2[rr * 4 + 2][b][kh] = a2;
        gs2[rr * 4 + 3][b][kh] = a3;
        __syncthreads();
        if (tid < 256) {
            int bb = tid & 31, hl_ = tid >> 5;
            int hg = wg * 8 + hl_;
            size_t prow = ((size_t)bb * T_ + t) * 2048;
            float gi = gs2[hl_][bb][0]      + gs2[hl_][bb][1]      + pre[prow + hg];
            float gf = gs2[8 + hl_][bb][0]  + gs2[8 + hl_][bb][1]  + pre[prow + 512 + hg];
            float gg = gs2[16 + hl_][bb][0] + gs2[16 + hl_][bb][1] + pre[prow + 1024 + hg];
            float go = gs2[24 + hl_][bb][0] + gs2[24 + hl_][bb][1] + pre[prow + 1536 + hg];
            float c = c_lds[hl_][bb];
            float cn = sigf(gf) * c + sigf(gi) * tanhf(gg);
            float hn = sigf(go) * tanhf(cn);
            c_lds[hl_][bb] = cn;
            hnew[bb * 512 + hg] = hn;
        }
        gbar(&bar[0], tgt);

        // ---------- S2: hl = tanh(Wlh h + blh) ----------
        gemv_stage<1>(Wlh, blh, hnew, hlbuf, Xs, p2, wg, tid);
        gbar(&bar[1], tgt);

        // ---------- S3: he = Weh hl + beh ----------
        gemv_stage<0>(Weh, beh, hlbuf, hebuf, Xs, p2, wg, tid);
        gbar(&bar[2], tgt);

        // ---------- S4: scores + softmax + u  (2 WGs per b) ----------
        {
            const int bb = wg >> 1, half = wg & 1;
            if (tid < 128) {
                float4 v = *(const float4*)(hebuf + bb * 512 + tid * 4);
                *(float4*)&hes_s[tid * 4] = v;
            }
            __syncthreads();
            for (int n0 = 0; n0 < 64; n0 += 32) {
                int n = n0 + (tid >> 4);
                if (n < 50) {
                    int hc = tid & 15;
                    const float* fe = feT + ((size_t)bb * N_ + n) * 512 + hc * 32;
                    const float* he = hes_s + hc * 32;
                    const float* wa = Wa + hc * 32;
                    float s = 0.f;
#pragma unroll
                    for (int q = 0; q < 32; ++q) s += wa[q] * tanhf(fe[q] + he[q]);
                    sp[n][hc] = s;
                }
            }
            __syncthreads();
            if (tid < 50) {
                float s = ba[0];
#pragma unroll
                for (int q = 0; q < 16; ++q) s += sp[tid][q];
                sc_s[tid] = s;
            }
            __syncthreads();
            if (tid < 64) {
                float v = (tid < 50) ? sc_s[tid] : -3.0e38f;
                float m = v;
#pragma unroll
                for (int s = 1; s < 64; s <<= 1) m = fmaxf(m, __shfl_xor(m, s, 64));
                float e = (tid < 50) ? expf(v - m) : 0.f;
                float su = e;
#pragma unroll
                for (int s = 1; s < 64; s <<= 1) su += __shfl_xor(su, s, 64);
                if (tid < 50) att_s[tid] = e / su;
            }
            __syncthreads();
            if (tid < 256) {
                int hg = half * 256 + tid;
                const float* fr = fl + ((size_t)bb * 512 + hg) * N_;
                float s = 0.f;
#pragma unroll
                for (int q = 0; q < 25; ++q) {
                    float2 v = *(const float2*)(fr + q * 2);
                    s += att_s[q * 2] * v.x + att_s[q * 2 + 1] * v.y;
                }
                ubuf[bb * 512 + hg] = s + hlbuf[bb * 512 + hg];
            }
        }
        gbar(&bar[3], tgt);

        // ---------- S5: vout = tanh(Wlo u + blo) ----------
        __syncthreads();
        stageX(Xs, ubuf, tid);
        __syncthreads();
        {
            int rp = tid >> 5, row = rp >> 1, khh = rp & 1;
            int rg = wg * 8 + row;
            const float* w = Wlo + (size_t)rg * 512 + khh * 256;
            const float* xb = Xs + b * 512;
            int gb2 = khh * 64;
            float s = 0.f;
#pragma unroll 8
            for (int q = 0; q < 64; ++q) {
                float4 xv = *(const float4*)(xb + (((gb2 + q) ^ (b & 7)) << 2));
                float4 wv = *(const float4*)(w + q * 4);
                s += wv.x * xv.x + wv.y * xv.y + wv.z * xv.z + wv.w * xv.w;
            }
            p2[row][b][khh] = s;
        }
        __syncthreads();
        if (tid < 256) {
            int bb = tid & 31, row = tid >> 5;
            int rg = wg * 8 + row;
            float vo = tanhf(p2[row][bb][0] + p2[row][bb][1] + blo[rg]);
            vout_cur[bb * 512 + rg] = vo;
            size_t orow = (size_t)bb * T_ + t;
            vout_all[orow * 512 + rg] = vo;
            vout_bf[orow * 512 + rg] = __float2bfloat16(vo);
        }
        gbar(&bar[4], tgt);
    }
}

// ---------------- phase 2: logits GEMM (bf16 MFMA) + tile maxes ----------------

#define LDT 56
__global__ __launch_bounds__(256) void k_logits(const __hip_bfloat16* __restrict__ A,
                                                const __hip_bfloat16* __restrict__ Bm,
                                                const float* __restrict__ bout,
                                                float* __restrict__ out,
                                                float* __restrict__ tilemax) {
    __shared__ __hip_bfloat16 As[128][LDT];
    __shared__ __hip_bfloat16 Bs[128][LDT];
    int m0 = blockIdx.x * 128, n0 = blockIdx.y * 128;
    int tid = threadIdx.x;
    int lane = tid & 63, w = tid >> 6, wr = w >> 1, wc = w & 1;
    f32x4 acc[4][4];
#pragma unroll
    for (int i = 0; i < 4; ++i)
#pragma unroll
        for (int j = 0; j < 4; ++j) acc[i][j] = (f32x4){0.f, 0.f, 0.f, 0.f};
    int srow = tid >> 2, skq = (tid & 3) * 8;
    for (int k0 = 0; k0 < 512; k0 += 32) {
        __syncthreads();
        *(uint4*)&As[srow][skq]      = *(const uint4*)(A + (size_t)(m0 + srow) * 512 + k0 + skq);
        *(uint4*)&As[srow + 64][skq] = *(const uint4*)(A + (size_t)(m0 + srow + 64) * 512 + k0 + skq);
        *(uint4*)&Bs[srow][skq]      = *(const uint4*)(Bm + (size_t)(n0 + srow) * 512 + k0 + skq);
        *(uint4*)&Bs[srow + 64][skq] = *(const uint4*)(Bm + (size_t)(n0 + srow + 64) * 512 + k0 + skq);
        __syncthreads();
        short8 av[4], bv[4];
#pragma unroll
        for (int m4 = 0; m4 < 4; ++m4)
            av[m4] = *(const short8*)&As[wr * 64 + m4 * 16 + (lane & 15)][(lane >> 4) * 8];
#pragma unroll
        for (int n4 = 0; n4 < 4; ++n4)
            bv[n4] = *(const short8*)&Bs[wc * 64 + n4 * 16 + (lane & 15)][(lane >> 4) * 8];
#pragma unroll
        for (int m4 = 0; m4 < 4; ++m4)
#pragma unroll
            for (int n4 = 0; n4 < 4; ++n4)
                acc[m4][n4] = __builtin_amdgcn_mfma_f32_16x16x32_bf16(av[m4], bv[n4], acc[m4][n4], 0, 0, 0);
    }
    float bo[4];
    int gcol4[4];
#pragma unroll
    for (int n4 = 0; n4 < 4; ++n4) {
        gcol4[n4] = n0 + wc * 64 + n4 * 16 + (lane & 15);
        bo[n4] = (gcol4[n4] < VM1) ? bout[gcol4[n4]] : 0.f;
    }
#pragma unroll
    for (int m4 = 0; m4 < 4; ++m4)
#pragma unroll
        for (int i = 0; i < 4; ++i) {
            size_t grow = m0 + wr * 64 + m4 * 16 + ((lane >> 4) << 2) + i;
            float rmax = -3.0e38f;
#pragma unroll
            for (int n4 = 0; n4 < 4; ++n4) {
                float val = acc[m4][n4][i] + bo[n4];
                if (gcol4[n4] < VM1) {
                    out[grow * VM1 + gcol4[n4]] = val;
                    rmax = fmaxf(rmax, val);
                }
            }
#pragma unroll
            for (int s = 1; s < 16; s <<= 1) rmax = fmaxf(rmax, __shfl_xor(rmax, s, 64));
            if ((lane & 15) == 0) tilemax[grow * 500 + (n0 >> 6) + wc] = rmax;
        }
}

// ---------------- phase 3: exact fp32 argmax refinement ----------------

__global__ __launch_bounds__(64) void k_argmax(const float* __restrict__ tilemax,
                                               const float* __restrict__ vout_all,
                                               const float* __restrict__ Wout,
                                               const float* __restrict__ bout,
                                               float* __restrict__ ids) {
    int r = blockIdx.x, lane = threadIdx.x;
    float m = -3.0e38f;
    for (int c = lane; c < 500; c += 64) m = fmaxf(m, tilemax[(size_t)r * 500 + c]);
#pragma unroll
    for (int s = 1; s < 64; s <<= 1) m = fmaxf(m, __shfl_xor(m, s, 64));
    float thr = m - DELTA_;
    float bestv = -3.0e38f;
    int bestj = 0x3fffffff;
    for (int c0 = 0; c0 < 500; c0 += 64) {
        int cc = c0 + lane;
        bool f = (cc < 500) && (tilemax[(size_t)r * 500 + cc] >= thr);
        unsigned long long mask = __ballot(f);
        while (mask) {
            int bit = __ffsll(mask) - 1;
            mask &= mask - 1;
            int chunk = c0 + bit;
            int j = chunk * 64 + lane;
            if (j < VM1) {
                const float* wr_ = Wout + (size_t)j * 512;
                const float* vr = vout_all + (size_t)r * 512;
                float s = 0.f;
#pragma unroll 4
                for (int k = 0; k < 128; ++k) {
                    float4 wv = *(const float4*)(wr_ + k * 4);
                    float4 vv = *(const float4*)(vr + k * 4);
                    s += wv.x * vv.x + wv.y * vv.y + wv.z * vv.z + wv.w * vv.w;
                }
                float val = s + bout[j];
                if (val > bestv || (val == bestv && j < bestj)) { bestv = val; bestj = j; }
            }
        }
    }
#pragma unroll
    for (int s = 1; s < 64; s <<= 1) {
        float ov = __shfl_xor(bestv, s, 64);
        int oj = __shfl_xor(bestj, s, 64);
        if (ov > bestv || (ov == bestv && oj < bestj)) { bestv = ov; bestj = oj; }
    }
    if (lane == 0) ids[r] = (float)bestj;
}

// ---------------- launcher ----------------

extern "C" void kernel_launch(void* const* d_in, const int* in_sizes, int n_in,
                              void* d_out, int out_size, void* d_ws, size_t ws_size,
                              hipStream_t stream) {
    const float* features = (const float*)d_in[0];
    const int* captions   = (const int*)d_in[2];
    const float* etab     = (const float*)d_in[3];
    const float* Wih      = (const float*)d_in[4];
    const float* bih      = (const float*)d_in[5];
    const float* Whh      = (const float*)d_in[6];
    const float* bhh      = (const float*)d_in[7];
    const float* Wf       = (const float*)d_in[8];
    const float* bf       = (const float*)d_in[9];
    const float* We       = (const float*)d_in[10];
    const float* be       = (const float*)d_in[11];
    const float* Wlh      = (const float*)d_in[12];
    const float* blh      = (const float*)d_in[13];
    const float* Weh      = (const float*)d_in[14];
    const float* beh      = (const float*)d_in[15];
    const float* Wa       = (const float*)d_in[16];
    const float* ba       = (const float*)d_in[17];
    const float* Wlo      = (const float*)d_in[18];
    const float* blo      = (const float*)d_in[19];
    const float* Wout     = (const float*)d_in[20];
    const float* bout     = (const float*)d_in[21];

    float* out = (float*)d_out;
    float* ids = out + (size_t)BT_ * VM1;

    char* ws = (char*)d_ws;
    size_t off = 0;
    auto alloc = [&](size_t bytes) {
        void* p = ws + off;
        off += (bytes + 255) & ~(size_t)255;
        return p;
    };
    float* pre      = (float*)alloc((size_t)BT_ * 2048 * 4);
    float* emb_mat  = (float*)alloc((size_t)BT_ * 512 * 4);
    float* fl       = (float*)alloc((size_t)B_ * 512 * 50 * 4);
    float* feT      = (float*)alloc((size_t)B_ * 50 * 512 * 4);
    float* vout_all = (float*)alloc((size_t)BT_ * 512 * 4);
    float* Hbuf     = (float*)alloc((size_t)2 * B_ * 512 * 4);
    float* vout_cur = (float*)alloc((size_t)B_ * 512 * 4);
    float* hlbuf    = (float*)alloc((size_t)B_ * 512 * 4);
    float* hebuf    = (float*)alloc((size_t)B_ * 512 * 4);
    float* ubuf     = (float*)alloc((size_t)B_ * 512 * 4);
    float* tilemax  = (float*)alloc((size_t)BT_ * 500 * 4);
    unsigned int* bar = (unsigned int*)alloc(256);
    __hip_bfloat16* wout_bf = (__hip_bfloat16*)alloc((size_t)V_ * 512 * 2);
    __hip_bfloat16* vout_bf = (__hip_bfloat16*)alloc((size_t)BT_ * 512 * 2);

    k_init<<<32, 512, 0, stream>>>(features, vout_cur, Hbuf, bar);
    k_gather<<<3200, 256, 0, stream>>>(captions, etab, emb_mat);
    k_fl<<<256, 256, 0, stream>>>(features, Wf, bf, fl);
    k_feT<<<256, 256, 0, stream>>>(fl, We, be, feT);
    k_pregemm<<<dim3(50, 32), 256, 0, stream>>>(emb_mat, Wih, bih, bhh, pre);
    k_wout_bf<<<8000, 256, 0, stream>>>(Wout, wout_bf);
    {
        void* args[] = { (void*)&Wih, (void*)&Whh, (void*)&Wlh, (void*)&blh,
                         (void*)&Weh, (void*)&beh, (void*)&Wa, (void*)&ba,
                         (void*)&Wlo, (void*)&blo, (void*)&pre, (void*)&fl, (void*)&feT,
                         (void*)&Hbuf, (void*)&vout_cur,
                         (void*)&hlbuf, (void*)&hebuf, (void*)&ubuf,
                         (void*)&vout_all, (void*)&vout_bf, (void*)&bar };
        hipLaunchCooperativeKernel((const void*)k_recur, dim3(G_), dim3(512), args, 0, stream);
    }
    k_logits<<<dim3(25, 250), 256, 0, stream>>>(vout_bf, wout_bf, bout, out, tilemax);
    k_argmax<<<3200, 64, 0, stream>>>(tilemax, vout_all, Wout, bout, ids);
}